// Round 2
// baseline (159.728 us; speedup 1.0000x reference)
//
#include <hip/hip_runtime.h>
#include <stdint.h>

// Problem dims (fixed by the reference)
#define NB   8192
#define NZ   10
#define CIN  512
#define COUT 512
#define MM   3
#define ALPHA 0.04419417382415922f   // 1/sqrt(512)

#define ROWS_TOTAL (NB * MM)          // 24576 GEMM rows (pos,d) d-fastest
#define BM 128
#define BN 128
#define BK 32
#define KITERS (CIN / BK)             // 16
#define MAX_MT (ROWS_TOTAL / BM + NZ) // 202
#define NGRP 32                       // histogram groups of 256 nodes

typedef short bf16x8 __attribute__((ext_vector_type(8)));
typedef float f32x4  __attribute__((ext_vector_type(4)));

__device__ __forceinline__ uint16_t f2bf(float f) {
    union { float f; uint32_t i; } v; v.f = f;
    uint32_t x = v.i;
    x += 0x7fffu + ((x >> 16) & 1u);   // RNE
    return (uint16_t)(x >> 16);
}
__device__ __forceinline__ uint32_t pack2(float a, float b) {
    return (uint32_t)f2bf(a) | ((uint32_t)f2bf(b) << 16);
}
__device__ __forceinline__ void async16(const ushort* g, ushort* l) {
    __builtin_amdgcn_global_load_lds((const uint32_t*)g, (uint32_t*)l, 16, 0, 0);
}

// ---- K0: blocks 0..31 decode species + per-group histogram;
//          blocks 32..1311 pack W fp32->bf16 -----------------------------
__global__ __launch_bounds__(256)
void prep_kernel(const float* __restrict__ attrs, const float* __restrict__ w,
                 int* __restrict__ species, int* __restrict__ hist,
                 ushort* __restrict__ wt) {
    const int tid = threadIdx.x;
    if (blockIdx.x >= NGRP) {
        // ---- pack_w: 1280 blocks x 256 threads x 8 elems
        const size_t i = ((size_t)(blockIdx.x - NGRP) * 256 + tid) * 8;
        float4 a = *(const float4*)(w + i);
        float4 b = *(const float4*)(w + i + 4);
        uint4 o;
        o.x = pack2(a.x, a.y); o.y = pack2(a.z, a.w);
        o.z = pack2(b.x, b.y); o.w = pack2(b.z, b.w);
        *(uint4*)(wt + i) = o;
        return;
    }
    // ---- decode + histogram (ballot, no atomics)
    __shared__ int wc[4][NZ];
    const int b = blockIdx.x * 256 + tid;
    const float* a = attrs + (size_t)b * NZ;
    int s = 0;
    #pragma unroll
    for (int z = 0; z < NZ; z++) if (a[z] > 0.5f) s = z;
    species[b] = s;
    const int wv = tid >> 6, lane = tid & 63;
    #pragma unroll
    for (int z = 0; z < NZ; z++) {
        unsigned long long m = __ballot(s == z);
        if (lane == 0) wc[wv][z] = __popcll(m);
    }
    __syncthreads();
    if (tid < NZ) {
        hist[blockIdx.x * NZ + tid] = wc[0][tid] + wc[1][tid] + wc[2][tid] + wc[3][tid];
    }
}

// ---- K1: place (deterministic, atomic-free). 32 blocks x 256.
__global__ __launch_bounds__(256)
void place_kernel(const int* __restrict__ species, const int* __restrict__ hist,
                  int* __restrict__ sorted, int* __restrict__ offsets,
                  int* __restrict__ tile_offsets) {
    __shared__ int lhist[NGRP][NZ];
    __shared__ int loff[NZ + 1], ltoff[NZ + 1];
    __shared__ int pb[NZ];
    __shared__ int wc[4][NZ];
    const int tid = threadIdx.x, g = blockIdx.x;

    // NGRP*NZ = 320 > 256 — strided load (tail was a crash in an earlier round)
    for (int i = tid; i < NGRP * NZ; i += 256) ((int*)lhist)[i] = hist[i];
    __syncthreads();
    if (tid == 0) {
        int off = 0, toff = 0;
        for (int z = 0; z < NZ; z++) {
            int tot = 0;
            for (int gg = 0; gg < NGRP; gg++) tot += lhist[gg][z];
            loff[z] = off; ltoff[z] = toff;
            off += tot;
            toff += (3 * tot + BM - 1) / BM;
        }
        loff[NZ] = off; ltoff[NZ] = toff;
    }
    __syncthreads();
    if (tid < NZ) {
        int base = loff[tid];
        for (int gg = 0; gg < g; gg++) base += lhist[gg][tid];
        pb[tid] = base;
    }
    if (g == 0 && tid < NZ + 1) {
        offsets[tid] = loff[tid];
        tile_offsets[tid] = ltoff[tid];
    }
    const int b = g * 256 + tid;
    const int s = species[b];
    const int wv = tid >> 6, lane = tid & 63;
    unsigned long long mymask = 0;
    #pragma unroll
    for (int z = 0; z < NZ; z++) {
        unsigned long long m = __ballot(s == z);
        if (lane == 0) wc[wv][z] = __popcll(m);
        if (s == z) mymask = m;
    }
    __syncthreads();
    int rank = __popcll(mymask & ((1ull << lane) - 1ull));
    #pragma unroll
    for (int w2 = 0; w2 < 4; w2++) if (w2 < wv) rank += wc[w2][s];
    sorted[pb[s] + rank] = b;
}

// ---- K2: pack t -> tt bf16, sorted order, d-major rows --------------------
// tt[3*p + d][c] = bf16(t[sorted[p]][c][d])
__global__ __launch_bounds__(256)
void pack_t(const float* __restrict__ t, const int* __restrict__ sorted,
            ushort* __restrict__ tt) {
    const int w = threadIdx.x >> 6, L = threadIdx.x & 63;
    const int p = blockIdx.x * 4 + w;
    const int node = sorted[p];
    const float4* src = (const float4*)(t + (size_t)node * (CIN * MM) + L * 24);
    float4 f[6];
    #pragma unroll
    for (int i = 0; i < 6; i++) f[i] = src[i];
    const float* v = (const float*)f;          // v[c_local*3 + d]
    #pragma unroll
    for (int d = 0; d < MM; d++) {
        uint4 o;
        o.x = pack2(v[d],      v[3 + d]);
        o.y = pack2(v[6 + d],  v[9 + d]);
        o.z = pack2(v[12 + d], v[15 + d]);
        o.w = pack2(v[18 + d], v[21 + d]);
        *(uint4*)&tt[(size_t)(3 * p + d) * CIN + L * 8] = o;
    }
}

// ---- K3: 128x128 MFMA GEMM over species segments --------------------------
// R1 changes:
//  (a) K-major LDS layout [q=k/8][row][8] -> conflict-free ds_read_b128
//      (was row-major [row][32]: 64B rows -> 8-way bank conflict, 1.6M cyc).
//      Staging stays gload_lds-linear: wave w stages k-slab q=w for all 128
//      rows (lane L -> row L / 64+L), per-lane GLOBAL address carries the
//      permutation (rule #21: layout change, both sides consistent).
//  (b) double-buffered prefetch (T3-minimum): issue next-tile staging first,
//      compute current, single __syncthreads (vmcnt(0) drain) per iter.
__global__ __launch_bounds__(256)
void gemm_kernel(const ushort* __restrict__ tt, const ushort* __restrict__ wt,
                 const int* __restrict__ sorted, const int* __restrict__ offsets,
                 const int* __restrict__ tile_offsets, float* __restrict__ out) {
    __shared__ ushort As[2][BK / 8][BM][8];   // 2 x 8 KB, K-major
    __shared__ ushort Bs[2][BK / 8][BN][8];   // 2 x 8 KB, K-major
    __shared__ int spos[48];                  // sorted[] slice for epilogue

    const int tz = blockIdx.x;
    if (tz >= tile_offsets[NZ]) return;
    int z = 0;
    #pragma unroll
    for (int i = 1; i < NZ; i++) if (tile_offsets[i] <= tz) z = i;

    const int row_base = 3 * offsets[z] + (tz - tile_offsets[z]) * BM;
    const int row_end  = 3 * offsets[z + 1];
    const int pos0     = row_base / 3;
    const int Cbase    = blockIdx.y * BN;

    const int tid = threadIdx.x;
    const int w = tid >> 6, L = tid & 63;

    if (tid < 48) spos[tid] = sorted[min(pos0 + tid, NB - 1)];

    // staging (K-major): wave w owns k-slab q=w (8 bf16 = 16B per row).
    // chunk 0: rows 0..63 (lane L -> row L), chunk 1: rows 64..127.
    const ushort* gA0 = tt + (size_t)(row_base + L) * CIN + w * 8;
    const ushort* gA1 = gA0 + (size_t)64 * CIN;
    const ushort* gB0 = wt + ((size_t)z * COUT + Cbase + L) * CIN + w * 8;
    const ushort* gB1 = gB0 + (size_t)64 * CIN;

    // compute: 2x2 wave grid; wave tile 64 rows x 64 cols
    const int wm = w & 1, wn = w >> 1;
    const int q = L >> 4, mr = L & 15;

    f32x4 acc[4][4];
    #pragma unroll
    for (int i = 0; i < 4; i++)
        #pragma unroll
        for (int j = 0; j < 4; j++) acc[i][j] = (f32x4){0.f, 0.f, 0.f, 0.f};

#define STAGE(bufi, ko) do {                       \
        async16(gA0 + (ko), &As[bufi][w][0][0]);   \
        async16(gA1 + (ko), &As[bufi][w][64][0]);  \
        async16(gB0 + (ko), &Bs[bufi][w][0][0]);   \
        async16(gB1 + (ko), &Bs[bufi][w][64][0]);  \
    } while (0)

    // prologue: stage k-tile 0 into buf 0; drain + barrier
    STAGE(0, 0);
    __syncthreads();

    for (int kt = 0; kt < KITERS; kt++) {
        const int cur = kt & 1;
        if (kt + 1 < KITERS) STAGE(cur ^ 1, (kt + 1) * BK);

        bf16x8 af[4], bf[4];
        #pragma unroll
        for (int am = 0; am < 4; am++)
            af[am] = *(const bf16x8*)&As[cur][q][wm * 64 + am * 16 + mr][0];
        #pragma unroll
        for (int bn = 0; bn < 4; bn++)
            bf[bn] = *(const bf16x8*)&Bs[cur][q][wn * 64 + bn * 16 + mr][0];
        #pragma unroll
        for (int am = 0; am < 4; am++)
            #pragma unroll
            for (int bn = 0; bn < 4; bn++)
                acc[am][bn] = __builtin_amdgcn_mfma_f32_16x16x32_bf16(
                    af[am], bf[bn], acc[am][bn], 0, 0, 0);

        // single barrier per iter: its vmcnt(0)/lgkmcnt(0) drain is the
        // T3-minimum counted point (prefetch latency hidden under compute)
        __syncthreads();
    }
#undef STAGE

    // epilogue: row -> (pos, d); out[node][C][d]
    #pragma unroll
    for (int am = 0; am < 4; am++) {
        #pragma unroll
        for (int r = 0; r < 4; r++) {
            const int Rg = row_base + wm * 64 + am * 16 + q * 4 + r;
            if (Rg < row_end) {
                const int pos = Rg / 3;
                const int d = Rg - 3 * pos;
                const int node = spos[pos - pos0];
                float* o = out + (size_t)node * (COUT * MM) + d;
                #pragma unroll
                for (int bn = 0; bn < 4; bn++) {
                    const int Cg = Cbase + wn * 64 + bn * 16 + mr;
                    o[(size_t)Cg * 3] = ALPHA * acc[am][bn][r];
                }
            }
        }
    }
}

extern "C" void kernel_launch(void* const* d_in, const int* in_sizes, int n_in,
                              void* d_out, int out_size, void* d_ws, size_t ws_size,
                              hipStream_t stream) {
    const float* t     = (const float*)d_in[0];   // [B, IN, 3]  fp32
    const float* attrs = (const float*)d_in[1];   // [B, Z]      fp32 one-hot
    const float* w     = (const float*)d_in[2];   // [Z, OUT, IN] fp32
    float* out = (float*)d_out;                   // [B, OUT, 3] fp32

    uint8_t* ws = (uint8_t*)d_ws;
    int* species      = (int*)ws;                  ws += NB * 4;
    int* sorted       = (int*)ws;                  ws += NB * 4;
    int* hist         = (int*)ws;                  ws += NGRP * NZ * 4;
    int* offsets      = (int*)ws;                  ws += 16 * 4;
    int* tile_offsets = (int*)ws;                  ws += 16 * 4;
    ws = (uint8_t*)(((uintptr_t)ws + 255) & ~(uintptr_t)255);
    ushort* wt = (ushort*)ws;                      ws += (size_t)NZ * COUT * CIN * 2;
    ushort* tt = (ushort*)ws;                      // ROWS_TOTAL+BM rows x CIN bf16

    // K0: 32 decode blocks + 1280 pack_w blocks
    hipLaunchKernelGGL(prep_kernel, dim3(NGRP + (NZ * COUT * CIN) / 2048), dim3(256),
                       0, stream, attrs, w, species, hist, wt);
    // K1: place (scan folded in, atomic-free)
    hipLaunchKernelGGL(place_kernel, dim3(NGRP), dim3(256), 0, stream,
                       species, hist, sorted, offsets, tile_offsets);
    // K2: pack t in sorted order
    hipLaunchKernelGGL(pack_t, dim3(NB / 4), dim3(256), 0, stream, t, sorted, tt);
    // K3: GEMM
    hipLaunchKernelGGL(gemm_kernel, dim3(MAX_MT, COUT / BN), dim3(256), 0, stream,
                       tt, wt, sorted, offsets, tile_offsets, out);
}

// Round 4
// 152.735 us; speedup vs baseline: 1.0458x; 1.0458x over previous
//
#include <hip/hip_runtime.h>
#include <stdint.h>

// Problem dims (fixed by the reference)
#define NB   8192
#define NZ   10
#define CIN  512
#define COUT 512
#define MM   3
#define ALPHA 0.04419417382415922f   // 1/sqrt(512)

#define ROWS_TOTAL (NB * MM)          // 24576 GEMM rows (pos,d) d-fastest
#define BM 128
#define BN 128
#define BK 32
#define KITERS (CIN / BK)             // 16
#define MAX_MT (ROWS_TOTAL / BM + NZ) // 202
#define NYB (COUT / BN)               // 4
#define NWG (MAX_MT * NYB)            // 808, divisible by 8 (T1 swizzle)
#define NGRP 32                       // histogram groups of 256 nodes

typedef short bf16x8 __attribute__((ext_vector_type(8)));
typedef float f32x4  __attribute__((ext_vector_type(4)));

__device__ __forceinline__ uint16_t f2bf(float f) {
    union { float f; uint32_t i; } v; v.f = f;
    uint32_t x = v.i;
    x += 0x7fffu + ((x >> 16) & 1u);   // RNE
    return (uint16_t)(x >> 16);
}
__device__ __forceinline__ uint32_t pack2(float a, float b) {
    return (uint32_t)f2bf(a) | ((uint32_t)f2bf(b) << 16);
}
__device__ __forceinline__ void async16(const void* g, void* l) {
    __builtin_amdgcn_global_load_lds((const uint32_t*)g, (uint32_t*)l, 16, 0, 0);
}

// ---- K0: blocks 0..31 decode species + per-group histogram;
//          blocks 32..1311 pack W fp32->bf16 (lane-contiguous, coalesced) ---
__global__ __launch_bounds__(256)
void prep_kernel(const float* __restrict__ attrs, const float* __restrict__ w,
                 int* __restrict__ species, int* __restrict__ hist,
                 ushort* __restrict__ wt) {
    const int tid = threadIdx.x;
    if (blockIdx.x >= NGRP) {
        // lane-contiguous float4 loads / uint2 stores (fully coalesced)
        const size_t base = (size_t)(blockIdx.x - NGRP) * 2048;
        const float* src = w + base;
        ushort* dst = wt + base;
        float4 a = *(const float4*)(src + tid * 4);
        float4 b = *(const float4*)(src + 1024 + tid * 4);
        uint2 oa, ob;
        oa.x = pack2(a.x, a.y); oa.y = pack2(a.z, a.w);
        ob.x = pack2(b.x, b.y); ob.y = pack2(b.z, b.w);
        *(uint2*)(dst + tid * 4) = oa;
        *(uint2*)(dst + 1024 + tid * 4) = ob;
        return;
    }
    // ---- decode + histogram (ballot, no atomics)
    __shared__ int wc[4][NZ];
    const int b = blockIdx.x * 256 + tid;
    const float* a = attrs + (size_t)b * NZ;
    int s = 0;
    #pragma unroll
    for (int z = 0; z < NZ; z++) if (a[z] > 0.5f) s = z;
    species[b] = s;
    const int wv = tid >> 6, lane = tid & 63;
    #pragma unroll
    for (int z = 0; z < NZ; z++) {
        unsigned long long m = __ballot(s == z);
        if (lane == 0) wc[wv][z] = __popcll(m);
    }
    __syncthreads();
    if (tid < NZ) {
        hist[blockIdx.x * NZ + tid] = wc[0][tid] + wc[1][tid] + wc[2][tid] + wc[3][tid];
    }
}

// ---- K1: place (deterministic, atomic-free). 32 blocks x 256.
__global__ __launch_bounds__(256)
void place_kernel(const int* __restrict__ species, const int* __restrict__ hist,
                  int* __restrict__ sorted, int* __restrict__ offsets,
                  int* __restrict__ tile_offsets) {
    __shared__ int lhist[NGRP][NZ];
    __shared__ int loff[NZ + 1], ltoff[NZ + 1];
    __shared__ int pb[NZ];
    __shared__ int wc[4][NZ];
    const int tid = threadIdx.x, g = blockIdx.x;

    for (int i = tid; i < NGRP * NZ; i += 256) ((int*)lhist)[i] = hist[i];
    __syncthreads();
    if (tid == 0) {
        int off = 0, toff = 0;
        for (int z = 0; z < NZ; z++) {
            int tot = 0;
            for (int gg = 0; gg < NGRP; gg++) tot += lhist[gg][z];
            loff[z] = off; ltoff[z] = toff;
            off += tot;
            toff += (3 * tot + BM - 1) / BM;
        }
        loff[NZ] = off; ltoff[NZ] = toff;
    }
    __syncthreads();
    if (tid < NZ) {
        int base = loff[tid];
        for (int gg = 0; gg < g; gg++) base += lhist[gg][tid];
        pb[tid] = base;
    }
    if (g == 0 && tid < NZ + 1) {
        offsets[tid] = loff[tid];
        tile_offsets[tid] = ltoff[tid];
    }
    const int b = g * 256 + tid;
    const int s = species[b];
    const int wv = tid >> 6, lane = tid & 63;
    unsigned long long mymask = 0;
    #pragma unroll
    for (int z = 0; z < NZ; z++) {
        unsigned long long m = __ballot(s == z);
        if (lane == 0) wc[wv][z] = __popcll(m);
        if (s == z) mymask = m;
    }
    __syncthreads();
    int rank = __popcll(mymask & ((1ull << lane) - 1ull));
    #pragma unroll
    for (int w2 = 0; w2 < 4; w2++) if (w2 < wv) rank += wc[w2][s];
    sorted[pb[s] + rank] = b;
}

// ---- K2: pack t -> tt bf16, sorted order, d-major rows --------------------
// tt[3*p + d][c] = bf16(t[sorted[p]][c][d])
// (R2-proven direct-load version; the LDS-bounce variant was untested risk.)
__global__ __launch_bounds__(256)
void pack_t(const float* __restrict__ t, const int* __restrict__ sorted,
            ushort* __restrict__ tt) {
    const int w = threadIdx.x >> 6, L = threadIdx.x & 63;
    const int p = blockIdx.x * 4 + w;
    const int node = sorted[p];
    const float4* src = (const float4*)(t + (size_t)node * (CIN * MM) + L * 24);
    float4 f[6];
    #pragma unroll
    for (int i = 0; i < 6; i++) f[i] = src[i];
    const float* v = (const float*)f;          // v[c_local*3 + d]
    #pragma unroll
    for (int d = 0; d < MM; d++) {
        uint4 o;
        o.x = pack2(v[d],      v[3 + d]);
        o.y = pack2(v[6 + d],  v[9 + d]);
        o.z = pack2(v[12 + d], v[15 + d]);
        o.w = pack2(v[18 + d], v[21 + d]);
        *(uint4*)&tt[(size_t)(3 * p + d) * CIN + L * 8] = o;
    }
}

// ---- K3: 128x128 MFMA GEMM over species segments --------------------------
//  * staging: row-major LDS [row][BK], LINEAR gload_lds dest, chunk-XOR
//    swizzle carried on the GLOBAL source (m173/T2): lane loads global chunk
//    c ^ ((row>>1)&3); ds_read applies the same XOR. Per 8-lane b128 phase
//    group this covers all 8 16B slots of the 128B window -> conflict-free,
//    and staging stays 16-full-line coalesced.
//  * pipeline: double-buffer + counted vmcnt(4) (T4) with raw s_barrier;
//    current iter's 4 prefetches stay in flight across the barrier.
//    Safety: vmcnt(4) means "<=4 outstanding"; tile kt+1's STAGE is the last
//    4 issued, so everything older (tile kt + compiler loads) has retired.
//  * T1 chunked XCD swizzle, y-fastest (A-tile read 4x by same XCD's L2).
//  * epilogue: acc -> LDS [16 pos][BN][3] fp32 chunks -> contiguous 1536B
//    per-node runs, 4B/lane lane-contiguous => full 64B lines, no RMW fetch.
__global__ __launch_bounds__(256)
void gemm_kernel(const ushort* __restrict__ tt, const ushort* __restrict__ wt,
                 const int* __restrict__ sorted, const int* __restrict__ offsets,
                 const int* __restrict__ tile_offsets, float* __restrict__ out) {
    // smem[0] = As dbuf, smem[1] = Bs dbuf (32 KB); epilogue reuses as float
    __shared__ __align__(16) ushort smem[2][2][BM][BK];
    __shared__ int spos[48];

    // T1: bijective chunked XCD swizzle (NWG % 8 == 0), y-fastest decode
    const int bid = blockIdx.x;
    const int nid = (bid & 7) * (NWG / 8) + (bid >> 3);
    const int tz = nid >> 2;
    const int Cbase = (nid & 3) * BN;

    if (tz >= tile_offsets[NZ]) return;
    int z = 0;
    #pragma unroll
    for (int i = 1; i < NZ; i++) if (tile_offsets[i] <= tz) z = i;

    const int row_base = 3 * offsets[z] + (tz - tile_offsets[z]) * BM;
    const int row_end  = 3 * offsets[z + 1];
    const int pos0     = row_base / 3;

    const int tid = threadIdx.x;
    const int w = tid >> 6, L = tid & 63;
    if (tid < 48) spos[tid] = sorted[min(pos0 + tid, NB - 1)];

    // staging: wave w -> rows [w*32, w*32+32) of A and B (2 instrs each).
    // lane L -> row lr=L>>2 (16 rows x 64B = 16 lines, coalesced), chunk
    // cs = (L&3) ^ ((L>>3)&3)  [= c ^ ((row>>1)&3), since (w*32)>>1 ≡ 0 mod 4]
    const int lr = L >> 2;
    const int cs = (L & 3) ^ ((L >> 3) & 3);
    const int soff = lr * CIN + cs * 8;
    const ushort* gA = tt + (size_t)(row_base + w * 32) * CIN + soff;
    const ushort* gB = wt + ((size_t)z * COUT + Cbase + w * 32) * CIN + soff;

    // compute: 2x2 wave grid; wave tile 64 rows x 64 cols
    const int wm = w & 1, wn = w >> 1;
    const int q = L >> 4, mr = L & 15;
    const int sr8 = (q ^ ((mr >> 1) & 3)) * 8;   // swizzled read slot (elems)

    f32x4 acc[4][4];
    #pragma unroll
    for (int i = 0; i < 4; i++)
        #pragma unroll
        for (int j = 0; j < 4; j++) acc[i][j] = (f32x4){0.f, 0.f, 0.f, 0.f};

#define STAGE(bufi, ko) do {                                        \
        async16(gA + (ko),                  &smem[0][bufi][w * 32][0]);      \
        async16(gA + 16 * CIN + (ko),       &smem[0][bufi][w * 32 + 16][0]); \
        async16(gB + (ko),                  &smem[1][bufi][w * 32][0]);      \
        async16(gB + 16 * CIN + (ko),       &smem[1][bufi][w * 32 + 16][0]); \
    } while (0)

    STAGE(0, 0);
    for (int kt = 0; kt < KITERS; kt++) {
        const int cur = kt & 1;
        if (kt + 1 < KITERS) {
            STAGE(cur ^ 1, (kt + 1) * BK);
            // wait only for tile kt's 4 loads (oldest); tile kt+1 stays in flight
            asm volatile("s_waitcnt vmcnt(4)" ::: "memory");
        } else {
            asm volatile("s_waitcnt vmcnt(0)" ::: "memory");
        }
        asm volatile("s_barrier" ::: "memory");   // all waves' tile-kt arrived

        bf16x8 af[4], bf[4];
        #pragma unroll
        for (int am = 0; am < 4; am++)
            af[am] = *(const bf16x8*)&smem[0][cur][wm * 64 + am * 16 + mr][sr8];
        #pragma unroll
        for (int bn = 0; bn < 4; bn++)
            bf[bn] = *(const bf16x8*)&smem[1][cur][wn * 64 + bn * 16 + mr][sr8];
        #pragma unroll
        for (int am = 0; am < 4; am++)
            #pragma unroll
            for (int bn = 0; bn < 4; bn++)
                acc[am][bn] = __builtin_amdgcn_mfma_f32_16x16x32_bf16(
                    af[am], bf[bn], acc[am][bn], 0, 0, 0);

        asm volatile("s_barrier" ::: "memory");   // reads done; next STAGE safe
    }
#undef STAGE

    // ---- epilogue: acc -> ebuf [16 pos][BN][3] -> full-line global stores
    float* ebuf = (float*)smem;          // 24 KB of the 32 KB staging LDS
    #pragma unroll
    for (int ch = 0; ch < 3; ch++) {
        __syncthreads();                 // ebuf free (K-loop / prev copy done)
        const int pbase = pos0 + ch * 16;
        #pragma unroll
        for (int am = 0; am < 4; am++) {
            #pragma unroll
            for (int r = 0; r < 4; r++) {
                const int Rg = row_base + wm * 64 + am * 16 + q * 4 + r;
                const int pos = Rg / 3;
                const int d = Rg - 3 * pos;
                const int lp = pos - pbase;
                if (lp >= 0 && lp < 16 && Rg < row_end) {
                    #pragma unroll
                    for (int bn = 0; bn < 4; bn++) {
                        const int c = wn * 64 + bn * 16 + mr;
                        ebuf[(lp * BN + c) * 3 + d] = ALPHA * acc[am][bn][r];
                    }
                }
            }
        }
        __syncthreads();
        // copy 16 pos x 384 floats; per-pos 1536B contiguous at out[node]
        #pragma unroll 4
        for (int j = 0; j < 24; j++) {
            const int idx = j * 256 + tid;           // 0..6143, lane-contiguous
            const int lp  = idx / 384;
            const int o   = idx - lp * 384;          // = c*3 + d
            const int pos = pbase + lp;
            const int d   = o % 3;
            const int row = 3 * pos + d;
            // ownership guard == exactly the slots written above
            if (row >= row_base && row < row_base + BM && row < row_end) {
                const int node = spos[pos - pos0];
                out[(size_t)node * (COUT * MM) + Cbase * 3 + o] = ebuf[idx];
            }
        }
    }
}

extern "C" void kernel_launch(void* const* d_in, const int* in_sizes, int n_in,
                              void* d_out, int out_size, void* d_ws, size_t ws_size,
                              hipStream_t stream) {
    const float* t     = (const float*)d_in[0];   // [B, IN, 3]  fp32
    const float* attrs = (const float*)d_in[1];   // [B, Z]      fp32 one-hot
    const float* w     = (const float*)d_in[2];   // [Z, OUT, IN] fp32
    float* out = (float*)d_out;                   // [B, OUT, 3] fp32

    uint8_t* ws = (uint8_t*)d_ws;
    int* species      = (int*)ws;                  ws += NB * 4;
    int* sorted       = (int*)ws;                  ws += NB * 4;
    int* hist         = (int*)ws;                  ws += NGRP * NZ * 4;
    int* offsets      = (int*)ws;                  ws += 16 * 4;
    int* tile_offsets = (int*)ws;                  ws += 16 * 4;
    ws = (uint8_t*)(((uintptr_t)ws + 255) & ~(uintptr_t)255);
    ushort* wt = (ushort*)ws;                      ws += (size_t)NZ * COUT * CIN * 2;
    ushort* tt = (ushort*)ws;                      // ROWS_TOTAL+BM rows x CIN bf16

    // K0: 32 decode blocks + 1280 pack_w blocks
    hipLaunchKernelGGL(prep_kernel, dim3(NGRP + (NZ * COUT * CIN) / 2048), dim3(256),
                       0, stream, attrs, w, species, hist, wt);
    // K1: place (scan folded in, atomic-free)
    hipLaunchKernelGGL(place_kernel, dim3(NGRP), dim3(256), 0, stream,
                       species, hist, sorted, offsets, tile_offsets);
    // K2: pack t in sorted order
    hipLaunchKernelGGL(pack_t, dim3(NB / 4), dim3(256), 0, stream, t, sorted, tt);
    // K3: GEMM (1-D grid for T1 swizzle)
    hipLaunchKernelGGL(gemm_kernel, dim3(NWG), dim3(256), 0, stream,
                       tt, wt, sorted, offsets, tile_offsets, out);
}